// Round 13
// baseline (593.570 us; speedup 1.0000x reference)
//
#include <hip/hip_runtime.h>

#define D_MODEL 1024
#define N_FEAT  16384
#define N_TOK   4096
#define K_TOP   64
#define CAP      256
#define CAND_MAX 256
#define DELTA    0.03f
#define ZTAU     2.40f

#define BM 128
#define BN 128
#define BK 64

typedef __attribute__((ext_vector_type(8))) short bf16x8;
typedef __attribute__((ext_vector_type(8))) unsigned short u16x8;
typedef __attribute__((ext_vector_type(4))) float f32x4;

// ---- helpers ----
__device__ __forceinline__ unsigned fkey(float f) {
    unsigned b = __float_as_uint(f);
    return (b & 0x80000000u) ? ~b : (b | 0x80000000u);
}
__device__ __forceinline__ float kinv(unsigned k) {
    unsigned b = (k & 0x80000000u) ? (k ^ 0x80000000u) : ~k;
    return __uint_as_float(b);
}
__device__ __forceinline__ unsigned short f2bf(float f) {
    unsigned u = __float_as_uint(f);
    return (unsigned short)((u + 0x7FFFu + ((u >> 16) & 1u)) >> 16);
}
__device__ __forceinline__ float bf2f(unsigned u) {
    return __uint_as_float(u << 16);
}
__device__ __forceinline__ unsigned fkey16(unsigned b) {
    return (b & 0x8000u) ? (~b & 0xFFFFu) : (b | 0x8000u);
}
__device__ __forceinline__ float kval16(unsigned k) {
    unsigned b = (k & 0x8000u) ? (k ^ 0x8000u) : (~k & 0xFFFFu);
    return bf2f(b);
}
__device__ __forceinline__ void gload_lds16(const void* g, void* l) {
    __builtin_amdgcn_global_load_lds(
        (const __attribute__((address_space(1))) void*)g,
        (__attribute__((address_space(3))) void*)l, 16, 0, 0);
}
__device__ __forceinline__ unsigned pack_cand(unsigned bits, int idx) {
    return (fkey16(bits) << 16) | (unsigned)(idx ^ 0x3FFF);
}
__device__ __forceinline__ int   cidx_of(unsigned p) { return (int)((p & 0xFFFFu) ^ 0x3FFFu); }
__device__ __forceinline__ float cval_of(unsigned p) { return kval16(p >> 16); }

// =====================================================================
// init: wsq = 0
// =====================================================================
__global__ void init_wsq(float* wsq) { if (threadIdx.x == 0) wsq[0] = 0.f; }

// =====================================================================
// Pure-stream zero fill of the sparse output region (r9-proven pattern).
// Keeps the 256 MB write stream OUT of the GEMM's L2s.
// =====================================================================
__global__ __launch_bounds__(256)
void zero_fill(float* __restrict__ sp, size_t n4)
{
    const f32x4 z = (f32x4){0.f, 0.f, 0.f, 0.f};
    const size_t stride = (size_t)gridDim.x * 256;
    for (size_t i = (size_t)blockIdx.x * 256 + threadIdx.x; i < n4; i += stride)
        ((f32x4*)sp)[i] = z;
}

// =====================================================================
// Fused: W -> bf16 AND sum-of-squares (one read of W)
// =====================================================================
__global__ __launch_bounds__(256)
void cvt_w_sq(const float* __restrict__ W, unsigned short* __restrict__ Wb,
              float* __restrict__ wsq, int n4)
{
    __shared__ float s_[4];
    const int tid = threadIdx.x, lane = tid & 63, wid = tid >> 6;
    float q = 0.f;
    for (int i = blockIdx.x * 256 + tid; i < n4; i += gridDim.x * 256) {
        float4 v = ((const float4*)W)[i];
        ushort4 o;
        o.x = f2bf(v.x); o.y = f2bf(v.y); o.z = f2bf(v.z); o.w = f2bf(v.w);
        ((ushort4*)Wb)[i] = o;
        q = fmaf(v.x, v.x, q); q = fmaf(v.y, v.y, q);
        q = fmaf(v.z, v.z, q); q = fmaf(v.w, v.w, q);
    }
    #pragma unroll
    for (int o = 32; o; o >>= 1) q += __shfl_down(q, o);
    if (lane == 0) s_[wid] = q;
    __syncthreads();
    if (tid == 0) atomicAdd(wsq, s_[0] + s_[1] + s_[2] + s_[3]);
}

// =====================================================================
// x -> bf16 + per-row tau = Z * ||x_row|| * sigma_w ; zero cnt[row]
// =====================================================================
__global__ __launch_bounds__(256)
void cvt_x_tau(const float* __restrict__ x, unsigned short* __restrict__ Xb,
               const float* __restrict__ wsq, float* __restrict__ tau,
               int* __restrict__ cnt, int nw_total)
{
    __shared__ float s_[4];
    const int row = blockIdx.x, tid = threadIdx.x;
    const int lane = tid & 63, wid = tid >> 6;
    float4 v = ((const float4*)x)[row * 256 + tid];
    ushort4 o;
    o.x = f2bf(v.x); o.y = f2bf(v.y); o.z = f2bf(v.z); o.w = f2bf(v.w);
    ((ushort4*)Xb)[row * 256 + tid] = o;
    float q = fmaf(v.x, v.x, fmaf(v.y, v.y, fmaf(v.z, v.z, v.w * v.w)));
    #pragma unroll
    for (int of = 32; of; of >>= 1) q += __shfl_down(q, of);
    if (lane == 0) s_[wid] = q;
    __syncthreads();
    if (tid == 0) {
        float sx = s_[0] + s_[1] + s_[2] + s_[3];
        tau[row] = ZTAU * sqrtf(sx * (wsq[0] / (float)nw_total));
        cnt[row] = 0;
    }
}

// =====================================================================
// Kernel 1: bf16 MFMA encode GEMM. Epilogue: candidate appends ONLY.
// No h materialization, no zero-write (done by zero_fill) -> L2 holds
// the GEMM panels. bm-fastest XCD mapping (r12).
// =====================================================================
__global__ __launch_bounds__(256)
void encode_fused(const unsigned short* __restrict__ Xb,
                  const unsigned short* __restrict__ Wb,
                  const float* __restrict__ be,
                  const float* __restrict__ taug,
                  int* __restrict__ cnt, unsigned* __restrict__ cand)
{
    __shared__ unsigned short Al[BM * BK];
    __shared__ unsigned short Bl[BN * BK];

    const int nwg = gridDim.x;
    const int per = nwg >> 3;
    const int sw  = (blockIdx.x & 7) * per + (blockIdx.x >> 3);
    const int bm  = sw & 31;                 // fastest: row block (shares Wb panel)
    const int bn  = sw >> 5;                 // 16 per XCD chunk, disjoint

    const int tid  = threadIdx.x;
    const int wid  = tid >> 6;
    const int lane = tid & 63;
    const int wr   = wid >> 1, wc = wid & 1;

    const size_t Abase = (size_t)(bm * BM) * D_MODEL;
    const size_t Bbase = (size_t)(bn * BN) * D_MODEL;

    f32x4 acc[4][4];
    #pragma unroll
    for (int m = 0; m < 4; ++m)
        #pragma unroll
        for (int n = 0; n < 4; ++n)
            acc[m][n] = (f32x4){0.f, 0.f, 0.f, 0.f};

    const int srow = (lane >> 3);
    const int scol = (lane & 7) * 8;

    for (int k0 = 0; k0 < D_MODEL; k0 += BK) {
        #pragma unroll
        for (int c4 = 0; c4 < 4; ++c4) {
            const int c   = wid * 4 + c4;
            const int row = c * 8 + srow;
            gload_lds16(Xb + Abase + (size_t)row * D_MODEL + k0 + scol, &Al[c * 512]);
            gload_lds16(Wb + Bbase + (size_t)row * D_MODEL + k0 + scol, &Bl[c * 512]);
        }
        __syncthreads();

        bf16x8 af[2][4], bf[2][4];
        const int kc = (lane >> 4) * 8;
        #pragma unroll
        for (int ks = 0; ks < 2; ++ks) {
            #pragma unroll
            for (int m = 0; m < 4; ++m)
                af[ks][m] = *(const bf16x8*)&Al[(wr * 64 + m * 16 + (lane & 15)) * BK + ks * 32 + kc];
            #pragma unroll
            for (int n = 0; n < 4; ++n)
                bf[ks][n] = *(const bf16x8*)&Bl[(wc * 64 + n * 16 + (lane & 15)) * BK + ks * 32 + kc];
        }
        #pragma unroll
        for (int ks = 0; ks < 2; ++ks)
            #pragma unroll
            for (int m = 0; m < 4; ++m)
                #pragma unroll
                for (int n = 0; n < 4; ++n)
                    acc[m][n] = __builtin_amdgcn_mfma_f32_16x16x32_bf16(af[ks][m], bf[ks][n], acc[m][n], 0, 0, 0);
        __syncthreads();
    }

    // ---- epilogue: candidate appends only
    const int c0 = bn * BN + wc * 64 + (lane & 15);
    #pragma unroll
    for (int m = 0; m < 4; ++m) {
        const int r0 = bm * BM + wr * 64 + m * 16 + (lane >> 4) * 4;
        #pragma unroll
        for (int r = 0; r < 4; ++r) {
            const int row = r0 + r;
            const float tau = taug[row];
            #pragma unroll
            for (int n = 0; n < 4; ++n) {
                const int col = c0 + n * 16;
                const unsigned bits = (unsigned)f2bf(acc[m][n][r] + be[col]);
                if (bf2f(bits) >= tau) {
                    int p = atomicAdd(&cnt[row], 1);
                    if (p < CAP)
                        cand[(size_t)row * CAP + p] = pack_cand(bits, col);
                }
            }
        }
    }
}

// =====================================================================
// Select+decode: exact top-64 from the candidate list. Fallback rescans
// RECOMPUTE the row (bf16 inputs, f32 accum) -- statistically never.
// f64 band refinement, deterministic slots, scatter, decode.
// =====================================================================
__global__ __launch_bounds__(256)
void select_decode(const float* __restrict__ x, const float* __restrict__ W,
                   const unsigned short* __restrict__ Wb,
                   const float* __restrict__ be, const float* __restrict__ bd,
                   const float* __restrict__ taug, const int* __restrict__ cntg,
                   const unsigned* __restrict__ candg, float* __restrict__ out)
{
    const int row = blockIdx.x, tid = threadIdx.x;
    const int lane = tid & 63, wid = tid >> 6;
    float* recon = out + (size_t)row * D_MODEL;
    float* srow  = out + (size_t)N_TOK * D_MODEL + (size_t)row * N_FEAT;

    __shared__ float    xs[D_MODEL];
    __shared__ unsigned cd[CAP];
    __shared__ double   v64[CAP];
    __shared__ int      tk_idx[K_TOP];
    __shared__ float    tk_val[K_TOP];
    __shared__ unsigned shT;
    __shared__ int      nc_sh, ns_sh;

    *(float4*)&xs[tid * 4] = *(const float4*)&x[(size_t)row * D_MODEL + tid * 4];
    if (tid < K_TOP) { tk_idx[tid] = -1; tk_val[tid] = 0.f; }

    int ncTrue = cntg[row];
    int nc = min(ncTrue, CAP);
    float thr = taug[row];
    if (tid < nc) cd[tid] = candg[(size_t)row * CAP + tid];
    __syncthreads();

    // ---- rare: adjust thr until 64 <= ncTrue <= CAP (recompute row)
    for (int t = 0; t < 10 && (ncTrue < K_TOP || ncTrue > CAP); ++t) {
        thr += (ncTrue > CAP) ? 0.08f : -0.08f;
        if (tid == 0) nc_sh = 0;
        __syncthreads();
        for (int f = tid; f < N_FEAT; f += 256) {
            const u16x8* wr8 = (const u16x8*)&Wb[(size_t)f * D_MODEL];
            float s = 0.f;
            for (int d8 = 0; d8 < D_MODEL / 8; ++d8) {
                u16x8 w8 = wr8[d8];
                #pragma unroll
                for (int k = 0; k < 8; ++k)
                    s = fmaf(bf2f((unsigned)(unsigned short)w8[k]),
                             bf2f((unsigned)f2bf(xs[d8 * 8 + k])), s);
            }
            unsigned bits = (unsigned)f2bf(s + be[f]);
            if (bf2f(bits) >= thr) {
                int p = atomicAdd(&nc_sh, 1);
                if (p < CAP) cd[p] = pack_cand(bits, f);
            }
        }
        __syncthreads();
        ncTrue = nc_sh; nc = min(ncTrue, CAP);
        __syncthreads();
    }

    // ---- T' = exact 64th largest (packed: value desc, idx asc)
    if (tid < nc) {
        unsigned me = cd[tid];
        int r = 0;
        for (int j = 0; j < nc; ++j) r += (cd[j] > me);
        if (r == K_TOP - 1) shT = me;
    }
    __syncthreads();
    const float Tval = cval_of(shT);

    // ---- rare: thr too high to cover the band -> one full recompute
    if (thr > Tval - DELTA) {
        const float thr2 = Tval - DELTA;
        if (tid == 0) nc_sh = 0;
        __syncthreads();
        for (int f = tid; f < N_FEAT; f += 256) {
            const u16x8* wr8 = (const u16x8*)&Wb[(size_t)f * D_MODEL];
            float s = 0.f;
            for (int d8 = 0; d8 < D_MODEL / 8; ++d8) {
                u16x8 w8 = wr8[d8];
                #pragma unroll
                for (int k = 0; k < 8; ++k)
                    s = fmaf(bf2f((unsigned)(unsigned short)w8[k]),
                             bf2f((unsigned)f2bf(xs[d8 * 8 + k])), s);
            }
            unsigned bits = (unsigned)f2bf(s + be[f]);
            if (bf2f(bits) >= thr2) {
                int p = atomicAdd(&nc_sh, 1);
                if (p < CAP) cd[p] = pack_cand(bits, f);
            }
        }
        __syncthreads();
        nc = min(nc_sh, CAP);
        __syncthreads();
    }

    // ---- classify
    if (tid == 0) ns_sh = 0;
    __syncthreads();
    const float sureT = Tval + DELTA, loT = Tval - DELTA;
    if (tid < nc && cval_of(cd[tid]) > sureT) atomicAdd(&ns_sh, 1);

    // ---- f64 refinement of the band (exact f32 inputs)
    for (int c = wid; c < nc; c += 4) {
        float cv = cval_of(cd[c]);
        if (cv > sureT || cv < loT) continue;
        int fi = cidx_of(cd[c]);
        const float* wr = &W[(size_t)fi * D_MODEL];
        double s = 0.0;
        #pragma unroll
        for (int e = 0; e < 16; ++e) {
            int d = lane + e * 64;
            s += (double)xs[d] * (double)wr[d];
        }
        #pragma unroll
        for (int o = 32; o; o >>= 1) s += __shfl_down(s, o);
        if (lane == 0) v64[c] = s + (double)be[fi];
    }
    __syncthreads();
    const int n_sure = ns_sh;

    // ---- deterministic slot assignment
    if (tid < nc) {
        const unsigned me = cd[tid];
        const float v = cval_of(me);
        const int fi = cidx_of(me);
        if (v > sureT) {
            int r = 0;
            for (int j = 0; j < nc; ++j) {
                unsigned cj = cd[j];
                r += (cval_of(cj) > sureT) && (cidx_of(cj) < fi);
            }
            tk_idx[r] = fi;
            tk_val[r] = fmaxf(v, 0.f);
        } else if (v >= loT) {
            const double mv = v64[tid];
            int r = 0;
            for (int j = 0; j < nc; ++j) {
                unsigned cj = cd[j];
                float vj = cval_of(cj);
                if (vj > sureT || vj < loT) continue;
                double xv = v64[j];
                r += (xv > mv) || (xv == mv && cidx_of(cj) < fi);
            }
            if (r < K_TOP - n_sure) {
                tk_idx[n_sure + r] = fi;
                tk_val[n_sure + r] = fmaxf((float)mv, 0.f);
            }
        }
    }
    __syncthreads();

    // ---- scatter the 64 sparse values (zeros already written by zero_fill)
    if (tid < K_TOP && tk_idx[tid] >= 0)
        srow[tk_idx[tid]] = tk_val[tid];

    // ---- decode: recon[d] = bd[d] + sum_j tk_val[j] * Wb[tk_idx[j]][d]
    const int d4 = tid * 4;
    float4 a = *(const float4*)&bd[d4];
    #pragma unroll 8
    for (int j = 0; j < K_TOP; ++j) {
        const float v = tk_val[j];
        const int ix = tk_idx[j] < 0 ? 0 : tk_idx[j];
        ushort4 w4 = *(const ushort4*)&Wb[(size_t)ix * D_MODEL + d4];
        a.x = fmaf(v, bf2f((unsigned)w4.x), a.x);
        a.y = fmaf(v, bf2f((unsigned)w4.y), a.y);
        a.z = fmaf(v, bf2f((unsigned)w4.z), a.z);
        a.w = fmaf(v, bf2f((unsigned)w4.w), a.w);
    }
    *(float4*)&recon[d4] = a;
}

// =====================================================================
// Tier C fallbacks (no workspace): f32 GEMM + f32 radix topk
// =====================================================================
__global__ __launch_bounds__(256)
void encode_gemm(const float* __restrict__ x, const float* __restrict__ W,
                 const float* __restrict__ be, float* __restrict__ h)
{
    __shared__ float As[32][68];
    __shared__ float Bs[32][68];

    const int bm = blockIdx.x % (N_TOK / 64);
    const int bn = blockIdx.x / (N_TOK / 64);
    const int tid = threadIdx.x;
    const int tx = tid & 15, ty = tid >> 4;

    const float* Ab = x + (size_t)(bm * 64) * D_MODEL;
    const float* Bb = W + (size_t)(bn * 64) * D_MODEL;

    float acc[4][4] = {};

    for (int k0 = 0; k0 < D_MODEL; k0 += 32) {
        #pragma unroll
        for (int i = 0; i < 8; ++i) {
            int e = tid + i * 256;
            int kk = e & 31, m = e >> 5;
            As[kk][m] = Ab[(size_t)m * D_MODEL + k0 + kk];
            Bs[kk][m] = Bb[(size_t)m * D_MODEL + k0 + kk];
        }
        __syncthreads();
        #pragma unroll
        for (int kk = 0; kk < 32; ++kk) {
            float4 a4 = *(const float4*)&As[kk][ty * 4];
            float4 b4 = *(const float4*)&Bs[kk][tx * 4];
            float a[4] = {a4.x, a4.y, a4.z, a4.w};
            float b[4] = {b4.x, b4.y, b4.z, b4.w};
            #pragma unroll
            for (int i = 0; i < 4; ++i)
                #pragma unroll
                for (int j = 0; j < 4; ++j)
                    acc[i][j] = fmaf(a[i], b[j], acc[i][j]);
        }
        __syncthreads();
    }

    const int rowb = bm * 64 + ty * 4;
    const int colb = bn * 64 + tx * 4;
    float4 bev = *(const float4*)&be[colb];
    float bb[4] = {bev.x, bev.y, bev.z, bev.w};
    #pragma unroll
    for (int i = 0; i < 4; ++i) {
        float4 o;
        o.x = acc[i][0] + bb[0];
        o.y = acc[i][1] + bb[1];
        o.z = acc[i][2] + bb[2];
        o.w = acc[i][3] + bb[3];
        *(float4*)&h[(size_t)(rowb + i) * N_FEAT + colb] = o;
    }
}

__global__ __launch_bounds__(256)
void topk_decode(const float* __restrict__ hsrc,
                 const float* __restrict__ x, const float* __restrict__ W,
                 const float* __restrict__ be, const float* __restrict__ bd,
                 float* __restrict__ out)
{
    const int row = blockIdx.x;
    const int tid = threadIdx.x;
    float* recon = out + (size_t)row * D_MODEL;
    float* srow  = out + (size_t)N_TOK * D_MODEL + (size_t)row * N_FEAT;
    const float* hr = hsrc + (size_t)row * N_FEAT;

    unsigned key[16][4];
    #pragma unroll
    for (int i = 0; i < 16; ++i) {
        float4 v = ((const float4*)hr)[tid + i * 256];
        key[i][0] = fkey(v.x); key[i][1] = fkey(v.y);
        key[i][2] = fkey(v.z); key[i][3] = fkey(v.w);
    }

    __shared__ unsigned hist[256];
    __shared__ unsigned sh_prefix;
    __shared__ int sh_need;
    __shared__ float xs[D_MODEL];
    __shared__ int      cand_idx[CAND_MAX];
    __shared__ unsigned cand_key[CAND_MAX];
    __shared__ double   cand_val[CAND_MAX];
    __shared__ int nc_sh, nsure_sh;
    __shared__ int   tk_idx[K_TOP];
    __shared__ float tk_val[K_TOP];

    *(float4*)&xs[tid * 4] = *(const float4*)&x[(size_t)row * D_MODEL + tid * 4];
    if (tid == 0) { nc_sh = 0; nsure_sh = 0; }
    if (tid < K_TOP) { tk_val[tid] = 0.0f; tk_idx[tid] = -1; }

    unsigned prefix = 0, maskv = 0;
    int need = K_TOP;
    for (int pass = 0; pass < 4; ++pass) {
        const int shift = 24 - 8 * pass;
        hist[tid] = 0;
        __syncthreads();
        #pragma unroll
        for (int i = 0; i < 16; ++i)
            #pragma unroll
            for (int j = 0; j < 4; ++j) {
                unsigned k = key[i][j];
                if ((k & maskv) == prefix)
                    atomicAdd(&hist[(k >> shift) & 255u], 1u);
            }
        __syncthreads();
        if (tid == 0) {
            unsigned cum = 0;
            int d = 255;
            for (; d >= 0; --d) {
                unsigned c = hist[d];
                if (cum + c >= (unsigned)need) break;
                cum += c;
            }
            if (d < 0) d = 0;
            sh_need = need - (int)cum;
            sh_prefix = prefix | ((unsigned)d << shift);
        }
        __syncthreads();
        prefix = sh_prefix;
        need = sh_need;
        maskv |= (0xFFu << shift);
    }
    const unsigned T  = prefix;
    const unsigned Tl = fkey(kinv(T) - DELTA);
    const unsigned Th = fkey(kinv(T) + DELTA);

    #pragma unroll
    for (int i = 0; i < 16; ++i)
        #pragma unroll
        for (int j = 0; j < 4; ++j)
            if (key[i][j] >= Tl) {
                int p = atomicAdd(&nc_sh, 1);
                if (p < CAND_MAX) {
                    cand_idx[p] = (tid + i * 256) * 4 + j;
                    cand_key[p] = key[i][j];
                }
            }
    __syncthreads();
    int nc = nc_sh; if (nc > CAND_MAX) nc = CAND_MAX;

    if (tid < nc && cand_key[tid] > Th) atomicAdd(&nsure_sh, 1);
    __syncthreads();
    const int n_sure = nsure_sh;

    {
        const int lane = tid & 63, wave = tid >> 6;
        for (int c = wave; c < nc; c += 4) {
            if (cand_key[c] > Th) continue;
            const float* wr = &W[(size_t)cand_idx[c] * D_MODEL];
            double s = 0.0;
            #pragma unroll
            for (int e = 0; e < 16; ++e) {
                int d = lane + e * 64;
                s += (double)xs[d] * (double)wr[d];
            }
            #pragma unroll
            for (int o = 32; o; o >>= 1) s += __shfl_down(s, o);
            if (lane == 0) cand_val[c] = s + (double)be[cand_idx[c]];
        }
    }
    __syncthreads();

    if (tid < nc) {
        const unsigned ki = cand_key[tid];
        const int fi = cand_idx[tid];
        if (ki > Th) {
            int r = 0;
            for (int j = 0; j < nc; ++j)
                r += (cand_key[j] > Th) && (cand_idx[j] < fi);
            tk_idx[r] = fi;
            tk_val[r] = fmaxf(kinv(ki), 0.0f);
        } else {
            const double v = cand_val[tid];
            int r = 0;
            for (int j = 0; j < nc; ++j) {
                if (cand_key[j] > Th) continue;
                double vj = cand_val[j];
                r += (vj > v) || (vj == v && cand_idx[j] < fi);
            }
            if (r < K_TOP - n_sure) {
                tk_idx[n_sure + r] = fi;
                tk_val[n_sure + r] = fmaxf((float)v, 0.0f);
            }
        }
    }
    __syncthreads();

    #pragma unroll
    for (int i = 0; i < 16; ++i) {
        float ov[4];
        #pragma unroll
        for (int j = 0; j < 4; ++j) {
            unsigned k = key[i][j];
            int f = (tid + i * 256) * 4 + j;
            float val = 0.0f;
            if (k >= Tl) {
                for (int q = 0; q < K_TOP; ++q)
                    if (tk_idx[q] == f) { val = tk_val[q]; break; }
            }
            ov[j] = val;
        }
        float4 o; o.x = ov[0]; o.y = ov[1]; o.z = ov[2]; o.w = ov[3];
        ((float4*)srow)[tid + i * 256] = o;
    }
    __syncthreads();

    const int d4 = tid * 4;
    float4 a = *(const float4*)&bd[d4];
    #pragma unroll 8
    for (int j = 0; j < K_TOP; ++j) {
        float v = tk_val[j];
        int ix = tk_idx[j] < 0 ? 0 : tk_idx[j];
        const float4 w = *(const float4*)&W[(size_t)ix * D_MODEL + d4];
        a.x = fmaf(v, w.x, a.x);
        a.y = fmaf(v, w.y, a.y);
        a.z = fmaf(v, w.z, a.z);
        a.w = fmaf(v, w.w, a.w);
    }
    *(float4*)&recon[d4] = a;
}

extern "C" void kernel_launch(void* const* d_in, const int* in_sizes, int n_in,
                              void* d_out, int out_size, void* d_ws, size_t ws_size,
                              hipStream_t stream) {
    const float* x     = (const float*)d_in[0];
    const float* W_enc = (const float*)d_in[1];
    const float* b_enc = (const float*)d_in[2];
    const float* b_dec = (const float*)d_in[4];
    float* out = (float*)d_out;

    float* h_out_region = out + (size_t)N_TOK * D_MODEL;

    const size_t nx = (size_t)N_TOK * D_MODEL;          // 4.19M
    const size_t nw = (size_t)N_FEAT * D_MODEL;         // 16.8M
    const size_t bf_bytes   = (nx + nw) * sizeof(unsigned short);     // 40 MB
    const size_t cand_bytes = (size_t)N_TOK * CAP * sizeof(unsigned); // 4 MB
    const size_t misc_bytes = (size_t)N_TOK * (sizeof(float) + sizeof(int)) + 64;
    const size_t needA = bf_bytes + cand_bytes + misc_bytes;          // ~44 MB

    if (ws_size >= needA) {
        // ---- tier A: no-h pipeline, streaming zero-fill decoupled from GEMM
        unsigned short* Xb  = (unsigned short*)d_ws;
        unsigned short* Wb  = Xb + nx;
        unsigned* cand = (unsigned*)((char*)d_ws + bf_bytes);
        float*    tau  = (float*)((char*)cand + cand_bytes);
        int*      cnt  = (int*)(tau + N_TOK);
        float*    wsq  = (float*)(cnt + N_TOK);

        init_wsq<<<1, 64, 0, stream>>>(wsq);
        zero_fill<<<2048, 256, 0, stream>>>(h_out_region,
                                            (size_t)N_TOK * N_FEAT / 4);
        cvt_w_sq<<<512, 256, 0, stream>>>(W_enc, Wb, wsq, (int)(nw / 4));
        cvt_x_tau<<<N_TOK, 256, 0, stream>>>(x, Xb, wsq, tau, cnt, (int)nw);
        encode_fused<<<(N_TOK / BM) * (N_FEAT / BN), 256, 0, stream>>>(
            Xb, Wb, b_enc, tau, cnt, cand);
        select_decode<<<N_TOK, 256, 0, stream>>>(x, W_enc, Wb, b_enc, b_dec,
                                                 tau, cnt, cand, out);
    } else {
        // ---- tier C: pure f32
        encode_gemm<<<(N_TOK / 64) * (N_FEAT / 64), 256, 0, stream>>>(x, W_enc, b_enc, h_out_region);
        topk_decode<<<N_TOK, 256, 0, stream>>>(h_out_region, x, W_enc, b_enc, b_dec, out);
    }
}

// Round 14
// 528.217 us; speedup vs baseline: 1.1237x; 1.1237x over previous
//
#include <hip/hip_runtime.h>

#define D_MODEL 1024
#define N_FEAT  16384
#define N_TOK   4096
#define K_TOP   64
#define CAP      256
#define CAND_MAX 256
#define DELTA    0.03f
#define ZTAU     2.40f

#define BM 128
#define BN 128
#define BK 64

typedef __attribute__((ext_vector_type(8))) short bf16x8;
typedef __attribute__((ext_vector_type(8))) unsigned short u16x8;
typedef __attribute__((ext_vector_type(4))) float f32x4;

// ---- helpers ----
__device__ __forceinline__ unsigned fkey(float f) {
    unsigned b = __float_as_uint(f);
    return (b & 0x80000000u) ? ~b : (b | 0x80000000u);
}
__device__ __forceinline__ float kinv(unsigned k) {
    unsigned b = (k & 0x80000000u) ? (k ^ 0x80000000u) : ~k;
    return __uint_as_float(b);
}
__device__ __forceinline__ unsigned short f2bf(float f) {
    unsigned u = __float_as_uint(f);
    return (unsigned short)((u + 0x7FFFu + ((u >> 16) & 1u)) >> 16);
}
__device__ __forceinline__ float bf2f(unsigned u) {
    return __uint_as_float(u << 16);
}
__device__ __forceinline__ unsigned fkey16(unsigned b) {
    return (b & 0x8000u) ? (~b & 0xFFFFu) : (b | 0x8000u);
}
__device__ __forceinline__ float kval16(unsigned k) {
    unsigned b = (k & 0x8000u) ? (k ^ 0x8000u) : (~k & 0xFFFFu);
    return bf2f(b);
}
__device__ __forceinline__ void gload_lds16(const void* g, void* l) {
    __builtin_amdgcn_global_load_lds(
        (const __attribute__((address_space(1))) void*)g,
        (__attribute__((address_space(3))) void*)l, 16, 0, 0);
}
__device__ __forceinline__ unsigned pack_cand(unsigned bits, int idx) {
    return (fkey16(bits) << 16) | (unsigned)(idx ^ 0x3FFF);
}
__device__ __forceinline__ int   cidx_of(unsigned p) { return (int)((p & 0xFFFFu) ^ 0x3FFFu); }
__device__ __forceinline__ float cval_of(unsigned p) { return kval16(p >> 16); }

// =====================================================================
// init: wsq = 0
// =====================================================================
__global__ void init_wsq(float* wsq) { if (threadIdx.x == 0) wsq[0] = 0.f; }

// =====================================================================
// Fused: W -> bf16 AND sum-of-squares (one read of W)
// =====================================================================
__global__ __launch_bounds__(256)
void cvt_w_sq(const float* __restrict__ W, unsigned short* __restrict__ Wb,
              float* __restrict__ wsq, int n4)
{
    __shared__ float s_[4];
    const int tid = threadIdx.x, lane = tid & 63, wid = tid >> 6;
    float q = 0.f;
    for (int i = blockIdx.x * 256 + tid; i < n4; i += gridDim.x * 256) {
        float4 v = ((const float4*)W)[i];
        ushort4 o;
        o.x = f2bf(v.x); o.y = f2bf(v.y); o.z = f2bf(v.z); o.w = f2bf(v.w);
        ((ushort4*)Wb)[i] = o;
        q = fmaf(v.x, v.x, q); q = fmaf(v.y, v.y, q);
        q = fmaf(v.z, v.z, q); q = fmaf(v.w, v.w, q);
    }
    #pragma unroll
    for (int o = 32; o; o >>= 1) q += __shfl_down(q, o);
    if (lane == 0) s_[wid] = q;
    __syncthreads();
    if (tid == 0) atomicAdd(wsq, s_[0] + s_[1] + s_[2] + s_[3]);
}

// =====================================================================
// x -> bf16 + per-row tau = Z * ||x_row|| * sigma_w ; zero cnt[row]
// =====================================================================
__global__ __launch_bounds__(256)
void cvt_x_tau(const float* __restrict__ x, unsigned short* __restrict__ Xb,
               const float* __restrict__ wsq, float* __restrict__ tau,
               int* __restrict__ cnt, int nw_total)
{
    __shared__ float s_[4];
    const int row = blockIdx.x, tid = threadIdx.x;
    const int lane = tid & 63, wid = tid >> 6;
    float4 v = ((const float4*)x)[row * 256 + tid];
    ushort4 o;
    o.x = f2bf(v.x); o.y = f2bf(v.y); o.z = f2bf(v.z); o.w = f2bf(v.w);
    ((ushort4*)Xb)[row * 256 + tid] = o;
    float q = fmaf(v.x, v.x, fmaf(v.y, v.y, fmaf(v.z, v.z, v.w * v.w)));
    #pragma unroll
    for (int of = 32; of; of >>= 1) q += __shfl_down(q, of);
    if (lane == 0) s_[wid] = q;
    __syncthreads();
    if (tid == 0) {
        float sx = s_[0] + s_[1] + s_[2] + s_[3];
        tau[row] = ZTAU * sqrtf(sx * (wsq[0] / (float)nw_total));
        cnt[row] = 0;
    }
}

// =====================================================================
// Kernel 1: bf16 MFMA encode GEMM.
//  - entry: nontemporal zero-write of this block's sparse region
//    (overlaps k-loop, bypasses L2 -> no panel eviction)
//  - 2D supertile XCD mapping: per-XCD chunk = 8bm x 4bn supertiles,
//    stn-fastest -> Xb (2MB/stm-group) persists in L2, Wb streams.
//  - epilogue: candidate appends only (no h materialization).
// =====================================================================
__global__ __launch_bounds__(256)
void encode_fused(const unsigned short* __restrict__ Xb,
                  const unsigned short* __restrict__ Wb,
                  const float* __restrict__ be,
                  const float* __restrict__ taug,
                  float* __restrict__ out,
                  int* __restrict__ cnt, unsigned* __restrict__ cand)
{
    __shared__ unsigned short Al[BM * BK];
    __shared__ unsigned short Bl[BN * BK];

    // ---- supertile mapping: 4096 blocks, 8 XCDs x 512, supertile 8bm x 4bn
    const int xcd = blockIdx.x & 7;
    const int c   = blockIdx.x >> 3;         // 0..511 within XCD (dispatch order)
    const int stm = c >> 7;                  // 0..3  (8-bm groups)
    const int r_  = c & 127;
    const int stn = r_ >> 5;                 // 0..3  (4-bn groups)
    const int w_  = r_ & 31;
    const int bm  = stm * 8 + (w_ & 7);      // 0..31
    const int bn  = xcd * 16 + stn * 4 + (w_ >> 3);  // 0..127

    const int tid  = threadIdx.x;
    const int wid  = tid >> 6;
    const int lane = tid & 63;
    const int wr   = wid >> 1, wc = wid & 1;

    // ---- nontemporal zero-write of this block's 128x128 sparse region
    {
        float* sp = out + (size_t)N_TOK * D_MODEL;
        const f32x4 z = (f32x4){0.f, 0.f, 0.f, 0.f};
        #pragma unroll
        for (int it = 0; it < 16; ++it) {
            int e = it * 256 + tid;            // 4096 f32x4 units = 128x128
            int rr = e >> 5;                   // 32 units per row
            int cB = e & 31;
            __builtin_nontemporal_store(
                z, (f32x4*)&sp[(size_t)(bm * BM + rr) * N_FEAT + bn * BN] + cB);
        }
    }

    const size_t Abase = (size_t)(bm * BM) * D_MODEL;
    const size_t Bbase = (size_t)(bn * BN) * D_MODEL;

    f32x4 acc[4][4];
    #pragma unroll
    for (int m = 0; m < 4; ++m)
        #pragma unroll
        for (int n = 0; n < 4; ++n)
            acc[m][n] = (f32x4){0.f, 0.f, 0.f, 0.f};

    const int srow = (lane >> 3);
    const int scol = (lane & 7) * 8;

    for (int k0 = 0; k0 < D_MODEL; k0 += BK) {
        #pragma unroll
        for (int c4 = 0; c4 < 4; ++c4) {
            const int cc  = wid * 4 + c4;
            const int row = cc * 8 + srow;
            gload_lds16(Xb + Abase + (size_t)row * D_MODEL + k0 + scol, &Al[cc * 512]);
            gload_lds16(Wb + Bbase + (size_t)row * D_MODEL + k0 + scol, &Bl[cc * 512]);
        }
        __syncthreads();

        bf16x8 af[2][4], bf[2][4];
        const int kc = (lane >> 4) * 8;
        #pragma unroll
        for (int ks = 0; ks < 2; ++ks) {
            #pragma unroll
            for (int m = 0; m < 4; ++m)
                af[ks][m] = *(const bf16x8*)&Al[(wr * 64 + m * 16 + (lane & 15)) * BK + ks * 32 + kc];
            #pragma unroll
            for (int n = 0; n < 4; ++n)
                bf[ks][n] = *(const bf16x8*)&Bl[(wc * 64 + n * 16 + (lane & 15)) * BK + ks * 32 + kc];
        }
        #pragma unroll
        for (int ks = 0; ks < 2; ++ks)
            #pragma unroll
            for (int m = 0; m < 4; ++m)
                #pragma unroll
                for (int n = 0; n < 4; ++n)
                    acc[m][n] = __builtin_amdgcn_mfma_f32_16x16x32_bf16(af[ks][m], bf[ks][n], acc[m][n], 0, 0, 0);
        __syncthreads();
    }

    // ---- epilogue: candidate appends only
    const int c0 = bn * BN + wc * 64 + (lane & 15);
    #pragma unroll
    for (int m = 0; m < 4; ++m) {
        const int r0 = bm * BM + wr * 64 + m * 16 + (lane >> 4) * 4;
        #pragma unroll
        for (int r = 0; r < 4; ++r) {
            const int row = r0 + r;
            const float tau = taug[row];
            #pragma unroll
            for (int n = 0; n < 4; ++n) {
                const int col = c0 + n * 16;
                const unsigned bits = (unsigned)f2bf(acc[m][n][r] + be[col]);
                if (bf2f(bits) >= tau) {
                    int p = atomicAdd(&cnt[row], 1);
                    if (p < CAP)
                        cand[(size_t)row * CAP + p] = pack_cand(bits, col);
                }
            }
        }
    }
}

// =====================================================================
// Select+decode: exact top-64 from the candidate list. Fallback rescans
// RECOMPUTE the row (bf16 inputs, f32 accum) -- statistically never.
// f64 band refinement, deterministic slots, scatter, decode.
// =====================================================================
__global__ __launch_bounds__(256)
void select_decode(const float* __restrict__ x, const float* __restrict__ W,
                   const unsigned short* __restrict__ Wb,
                   const float* __restrict__ be, const float* __restrict__ bd,
                   const float* __restrict__ taug, const int* __restrict__ cntg,
                   const unsigned* __restrict__ candg, float* __restrict__ out)
{
    const int row = blockIdx.x, tid = threadIdx.x;
    const int lane = tid & 63, wid = tid >> 6;
    float* recon = out + (size_t)row * D_MODEL;
    float* srow  = out + (size_t)N_TOK * D_MODEL + (size_t)row * N_FEAT;

    __shared__ float    xs[D_MODEL];
    __shared__ unsigned cd[CAP];
    __shared__ double   v64[CAP];
    __shared__ int      tk_idx[K_TOP];
    __shared__ float    tk_val[K_TOP];
    __shared__ unsigned shT;
    __shared__ int      nc_sh, ns_sh;

    *(float4*)&xs[tid * 4] = *(const float4*)&x[(size_t)row * D_MODEL + tid * 4];
    if (tid < K_TOP) { tk_idx[tid] = -1; tk_val[tid] = 0.f; }

    int ncTrue = cntg[row];
    int nc = min(ncTrue, CAP);
    float thr = taug[row];
    if (tid < nc) cd[tid] = candg[(size_t)row * CAP + tid];
    __syncthreads();

    // ---- rare: adjust thr until 64 <= ncTrue <= CAP (recompute row)
    for (int t = 0; t < 10 && (ncTrue < K_TOP || ncTrue > CAP); ++t) {
        thr += (ncTrue > CAP) ? 0.08f : -0.08f;
        if (tid == 0) nc_sh = 0;
        __syncthreads();
        for (int f = tid; f < N_FEAT; f += 256) {
            const u16x8* wr8 = (const u16x8*)&Wb[(size_t)f * D_MODEL];
            float s = 0.f;
            for (int d8 = 0; d8 < D_MODEL / 8; ++d8) {
                u16x8 w8 = wr8[d8];
                #pragma unroll
                for (int k = 0; k < 8; ++k)
                    s = fmaf(bf2f((unsigned)(unsigned short)w8[k]),
                             bf2f((unsigned)f2bf(xs[d8 * 8 + k])), s);
            }
            unsigned bits = (unsigned)f2bf(s + be[f]);
            if (bf2f(bits) >= thr) {
                int p = atomicAdd(&nc_sh, 1);
                if (p < CAP) cd[p] = pack_cand(bits, f);
            }
        }
        __syncthreads();
        ncTrue = nc_sh; nc = min(ncTrue, CAP);
        __syncthreads();
    }

    // ---- T' = exact 64th largest (packed: value desc, idx asc)
    if (tid < nc) {
        unsigned me = cd[tid];
        int r = 0;
        for (int j = 0; j < nc; ++j) r += (cd[j] > me);
        if (r == K_TOP - 1) shT = me;
    }
    __syncthreads();
    const float Tval = cval_of(shT);

    // ---- rare: thr too high to cover the band -> one full recompute
    if (thr > Tval - DELTA) {
        const float thr2 = Tval - DELTA;
        if (tid == 0) nc_sh = 0;
        __syncthreads();
        for (int f = tid; f < N_FEAT; f += 256) {
            const u16x8* wr8 = (const u16x8*)&Wb[(size_t)f * D_MODEL];
            float s = 0.f;
            for (int d8 = 0; d8 < D_MODEL / 8; ++d8) {
                u16x8 w8 = wr8[d8];
                #pragma unroll
                for (int k = 0; k < 8; ++k)
                    s = fmaf(bf2f((unsigned)(unsigned short)w8[k]),
                             bf2f((unsigned)f2bf(xs[d8 * 8 + k])), s);
            }
            unsigned bits = (unsigned)f2bf(s + be[f]);
            if (bf2f(bits) >= thr2) {
                int p = atomicAdd(&nc_sh, 1);
                if (p < CAP) cd[p] = pack_cand(bits, f);
            }
        }
        __syncthreads();
        nc = min(nc_sh, CAP);
        __syncthreads();
    }

    // ---- classify
    if (tid == 0) ns_sh = 0;
    __syncthreads();
    const float sureT = Tval + DELTA, loT = Tval - DELTA;
    if (tid < nc && cval_of(cd[tid]) > sureT) atomicAdd(&ns_sh, 1);

    // ---- f64 refinement of the band (exact f32 inputs)
    for (int c = wid; c < nc; c += 4) {
        float cv = cval_of(cd[c]);
        if (cv > sureT || cv < loT) continue;
        int fi = cidx_of(cd[c]);
        const float* wr = &W[(size_t)fi * D_MODEL];
        double s = 0.0;
        #pragma unroll
        for (int e = 0; e < 16; ++e) {
            int d = lane + e * 64;
            s += (double)xs[d] * (double)wr[d];
        }
        #pragma unroll
        for (int o = 32; o; o >>= 1) s += __shfl_down(s, o);
        if (lane == 0) v64[c] = s + (double)be[fi];
    }
    __syncthreads();
    const int n_sure = ns_sh;

    // ---- deterministic slot assignment
    if (tid < nc) {
        const unsigned me = cd[tid];
        const float v = cval_of(me);
        const int fi = cidx_of(me);
        if (v > sureT) {
            int r = 0;
            for (int j = 0; j < nc; ++j) {
                unsigned cj = cd[j];
                r += (cval_of(cj) > sureT) && (cidx_of(cj) < fi);
            }
            tk_idx[r] = fi;
            tk_val[r] = fmaxf(v, 0.f);
        } else if (v >= loT) {
            const double mv = v64[tid];
            int r = 0;
            for (int j = 0; j < nc; ++j) {
                unsigned cj = cd[j];
                float vj = cval_of(cj);
                if (vj > sureT || vj < loT) continue;
                double xv = v64[j];
                r += (xv > mv) || (xv == mv && cidx_of(cj) < fi);
            }
            if (r < K_TOP - n_sure) {
                tk_idx[n_sure + r] = fi;
                tk_val[n_sure + r] = fmaxf((float)mv, 0.f);
            }
        }
    }
    __syncthreads();

    // ---- scatter the 64 sparse values (zeros already written by encode)
    if (tid < K_TOP && tk_idx[tid] >= 0)
        srow[tk_idx[tid]] = tk_val[tid];

    // ---- decode: recon[d] = bd[d] + sum_j tk_val[j] * Wb[tk_idx[j]][d]
    const int d4 = tid * 4;
    float4 a = *(const float4*)&bd[d4];
    #pragma unroll 8
    for (int j = 0; j < K_TOP; ++j) {
        const float v = tk_val[j];
        const int ix = tk_idx[j] < 0 ? 0 : tk_idx[j];
        ushort4 w4 = *(const ushort4*)&Wb[(size_t)ix * D_MODEL + d4];
        a.x = fmaf(v, bf2f((unsigned)w4.x), a.x);
        a.y = fmaf(v, bf2f((unsigned)w4.y), a.y);
        a.z = fmaf(v, bf2f((unsigned)w4.z), a.z);
        a.w = fmaf(v, bf2f((unsigned)w4.w), a.w);
    }
    *(float4*)&recon[d4] = a;
}

// =====================================================================
// Tier C fallbacks (no workspace): f32 GEMM + f32 radix topk
// =====================================================================
__global__ __launch_bounds__(256)
void encode_gemm(const float* __restrict__ x, const float* __restrict__ W,
                 const float* __restrict__ be, float* __restrict__ h)
{
    __shared__ float As[32][68];
    __shared__ float Bs[32][68];

    const int bm = blockIdx.x % (N_TOK / 64);
    const int bn = blockIdx.x / (N_TOK / 64);
    const int tid = threadIdx.x;
    const int tx = tid & 15, ty = tid >> 4;

    const float* Ab = x + (size_t)(bm * 64) * D_MODEL;
    const float* Bb = W + (size_t)(bn * 64) * D_MODEL;

    float acc[4][4] = {};

    for (int k0 = 0; k0 < D_MODEL; k0 += 32) {
        #pragma unroll
        for (int i = 0; i < 8; ++i) {
            int e = tid + i * 256;
            int kk = e & 31, m = e >> 5;
            As[kk][m] = Ab[(size_t)m * D_MODEL + k0 + kk];
            Bs[kk][m] = Bb[(size_t)m * D_MODEL + k0 + kk];
        }
        __syncthreads();
        #pragma unroll
        for (int kk = 0; kk < 32; ++kk) {
            float4 a4 = *(const float4*)&As[kk][ty * 4];
            float4 b4 = *(const float4*)&Bs[kk][tx * 4];
            float a[4] = {a4.x, a4.y, a4.z, a4.w};
            float b[4] = {b4.x, b4.y, b4.z, b4.w};
            #pragma unroll
            for (int i = 0; i < 4; ++i)
                #pragma unroll
                for (int j = 0; j < 4; ++j)
                    acc[i][j] = fmaf(a[i], b[j], acc[i][j]);
        }
        __syncthreads();
    }

    const int rowb = bm * 64 + ty * 4;
    const int colb = bn * 64 + tx * 4;
    float4 bev = *(const float4*)&be[colb];
    float bb[4] = {bev.x, bev.y, bev.z, bev.w};
    #pragma unroll
    for (int i = 0; i < 4; ++i) {
        float4 o;
        o.x = acc[i][0] + bb[0];
        o.y = acc[i][1] + bb[1];
        o.z = acc[i][2] + bb[2];
        o.w = acc[i][3] + bb[3];
        *(float4*)&h[(size_t)(rowb + i) * N_FEAT + colb] = o;
    }
}

__global__ __launch_bounds__(256)
void topk_decode(const float* __restrict__ hsrc,
                 const float* __restrict__ x, const float* __restrict__ W,
                 const float* __restrict__ be, const float* __restrict__ bd,
                 float* __restrict__ out)
{
    const int row = blockIdx.x;
    const int tid = threadIdx.x;
    float* recon = out + (size_t)row * D_MODEL;
    float* srow  = out + (size_t)N_TOK * D_MODEL + (size_t)row * N_FEAT;
    const float* hr = hsrc + (size_t)row * N_FEAT;

    unsigned key[16][4];
    #pragma unroll
    for (int i = 0; i < 16; ++i) {
        float4 v = ((const float4*)hr)[tid + i * 256];
        key[i][0] = fkey(v.x); key[i][1] = fkey(v.y);
        key[i][2] = fkey(v.z); key[i][3] = fkey(v.w);
    }

    __shared__ unsigned hist[256];
    __shared__ unsigned sh_prefix;
    __shared__ int sh_need;
    __shared__ float xs[D_MODEL];
    __shared__ int      cand_idx[CAND_MAX];
    __shared__ unsigned cand_key[CAND_MAX];
    __shared__ double   cand_val[CAND_MAX];
    __shared__ int nc_sh, nsure_sh;
    __shared__ int   tk_idx[K_TOP];
    __shared__ float tk_val[K_TOP];

    *(float4*)&xs[tid * 4] = *(const float4*)&x[(size_t)row * D_MODEL + tid * 4];
    if (tid == 0) { nc_sh = 0; nsure_sh = 0; }
    if (tid < K_TOP) { tk_val[tid] = 0.0f; tk_idx[tid] = -1; }

    unsigned prefix = 0, maskv = 0;
    int need = K_TOP;
    for (int pass = 0; pass < 4; ++pass) {
        const int shift = 24 - 8 * pass;
        hist[tid] = 0;
        __syncthreads();
        #pragma unroll
        for (int i = 0; i < 16; ++i)
            #pragma unroll
            for (int j = 0; j < 4; ++j) {
                unsigned k = key[i][j];
                if ((k & maskv) == prefix)
                    atomicAdd(&hist[(k >> shift) & 255u], 1u);
            }
        __syncthreads();
        if (tid == 0) {
            unsigned cum = 0;
            int d = 255;
            for (; d >= 0; --d) {
                unsigned c = hist[d];
                if (cum + c >= (unsigned)need) break;
                cum += c;
            }
            if (d < 0) d = 0;
            sh_need = need - (int)cum;
            sh_prefix = prefix | ((unsigned)d << shift);
        }
        __syncthreads();
        prefix = sh_prefix;
        need = sh_need;
        maskv |= (0xFFu << shift);
    }
    const unsigned T  = prefix;
    const unsigned Tl = fkey(kinv(T) - DELTA);
    const unsigned Th = fkey(kinv(T) + DELTA);

    #pragma unroll
    for (int i = 0; i < 16; ++i)
        #pragma unroll
        for (int j = 0; j < 4; ++j)
            if (key[i][j] >= Tl) {
                int p = atomicAdd(&nc_sh, 1);
                if (p < CAND_MAX) {
                    cand_idx[p] = (tid + i * 256) * 4 + j;
                    cand_key[p] = key[i][j];
                }
            }
    __syncthreads();
    int nc = nc_sh; if (nc > CAND_MAX) nc = CAND_MAX;

    if (tid < nc && cand_key[tid] > Th) atomicAdd(&nsure_sh, 1);
    __syncthreads();
    const int n_sure = nsure_sh;

    {
        const int lane = tid & 63, wave = tid >> 6;
        for (int c = wave; c < nc; c += 4) {
            if (cand_key[c] > Th) continue;
            const float* wr = &W[(size_t)cand_idx[c] * D_MODEL];
            double s = 0.0;
            #pragma unroll
            for (int e = 0; e < 16; ++e) {
                int d = lane + e * 64;
                s += (double)xs[d] * (double)wr[d];
            }
            #pragma unroll
            for (int o = 32; o; o >>= 1) s += __shfl_down(s, o);
            if (lane == 0) cand_val[c] = s + (double)be[cand_idx[c]];
        }
    }
    __syncthreads();

    if (tid < nc) {
        const unsigned ki = cand_key[tid];
        const int fi = cand_idx[tid];
        if (ki > Th) {
            int r = 0;
            for (int j = 0; j < nc; ++j)
                r += (cand_key[j] > Th) && (cand_idx[j] < fi);
            tk_idx[r] = fi;
            tk_val[r] = fmaxf(kinv(ki), 0.0f);
        } else {
            const double v = cand_val[tid];
            int r = 0;
            for (int j = 0; j < nc; ++j) {
                if (cand_key[j] > Th) continue;
                double vj = cand_val[j];
                r += (vj > v) || (vj == v && cand_idx[j] < fi);
            }
            if (r < K_TOP - n_sure) {
                tk_idx[n_sure + r] = fi;
                tk_val[n_sure + r] = fmaxf((float)v, 0.0f);
            }
        }
    }
    __syncthreads();

    #pragma unroll
    for (int i = 0; i < 16; ++i) {
        float ov[4];
        #pragma unroll
        for (int j = 0; j < 4; ++j) {
            unsigned k = key[i][j];
            int f = (tid + i * 256) * 4 + j;
            float val = 0.0f;
            if (k >= Tl) {
                for (int q = 0; q < K_TOP; ++q)
                    if (tk_idx[q] == f) { val = tk_val[q]; break; }
            }
            ov[j] = val;
        }
        float4 o; o.x = ov[0]; o.y = ov[1]; o.z = ov[2]; o.w = ov[3];
        ((float4*)srow)[tid + i * 256] = o;
    }
    __syncthreads();

    const int d4 = tid * 4;
    float4 a = *(const float4*)&bd[d4];
    #pragma unroll 8
    for (int j = 0; j < K_TOP; ++j) {
        float v = tk_val[j];
        int ix = tk_idx[j] < 0 ? 0 : tk_idx[j];
        const float4 w = *(const float4*)&W[(size_t)ix * D_MODEL + d4];
        a.x = fmaf(v, w.x, a.x);
        a.y = fmaf(v, w.y, a.y);
        a.z = fmaf(v, w.z, a.z);
        a.w = fmaf(v, w.w, a.w);
    }
    *(float4*)&recon[d4] = a;
}

extern "C" void kernel_launch(void* const* d_in, const int* in_sizes, int n_in,
                              void* d_out, int out_size, void* d_ws, size_t ws_size,
                              hipStream_t stream) {
    const float* x     = (const float*)d_in[0];
    const float* W_enc = (const float*)d_in[1];
    const float* b_enc = (const float*)d_in[2];
    const float* b_dec = (const float*)d_in[4];
    float* out = (float*)d_out;

    float* h_out_region = out + (size_t)N_TOK * D_MODEL;

    const size_t nx = (size_t)N_TOK * D_MODEL;          // 4.19M
    const size_t nw = (size_t)N_FEAT * D_MODEL;         // 16.8M
    const size_t bf_bytes   = (nx + nw) * sizeof(unsigned short);     // 40 MB
    const size_t cand_bytes = (size_t)N_TOK * CAP * sizeof(unsigned); // 4 MB
    const size_t misc_bytes = (size_t)N_TOK * (sizeof(float) + sizeof(int)) + 64;
    const size_t needA = bf_bytes + cand_bytes + misc_bytes;          // ~44 MB

    if (ws_size >= needA) {
        // ---- tier A: no-h pipeline, zeros fused into encode (nt stores)
        unsigned short* Xb  = (unsigned short*)d_ws;
        unsigned short* Wb  = Xb + nx;
        unsigned* cand = (unsigned*)((char*)d_ws + bf_bytes);
        float*    tau  = (float*)((char*)cand + cand_bytes);
        int*      cnt  = (int*)(tau + N_TOK);
        float*    wsq  = (float*)(cnt + N_TOK);

        init_wsq<<<1, 64, 0, stream>>>(wsq);
        cvt_w_sq<<<512, 256, 0, stream>>>(W_enc, Wb, wsq, (int)(nw / 4));
        cvt_x_tau<<<N_TOK, 256, 0, stream>>>(x, Xb, wsq, tau, cnt, (int)nw);
        encode_fused<<<(N_TOK / BM) * (N_FEAT / BN), 256, 0, stream>>>(
            Xb, Wb, b_enc, tau, out, cnt, cand);
        select_decode<<<N_TOK, 256, 0, stream>>>(x, W_enc, Wb, b_enc, b_dec,
                                                 tau, cnt, cand, out);
    } else {
        // ---- tier C: pure f32
        encode_gemm<<<(N_TOK / 64) * (N_FEAT / 64), 256, 0, stream>>>(x, W_enc, b_enc, h_out_region);
        topk_decode<<<N_TOK, 256, 0, stream>>>(h_out_region, x, W_enc, b_enc, b_dec, out);
    }
}

// Round 15
// 506.567 us; speedup vs baseline: 1.1718x; 1.0427x over previous
//
#include <hip/hip_runtime.h>

#define D_MODEL 1024
#define N_FEAT  16384
#define N_TOK   4096
#define K_TOP   64
#define CAP      256
#define CAND_MAX 256
#define DELTA    0.03f
#define ZTAU     2.40f

#define BM 128
#define BN 128
#define BK 64

typedef __attribute__((ext_vector_type(8))) short bf16x8;
typedef __attribute__((ext_vector_type(8))) unsigned short u16x8;
typedef __attribute__((ext_vector_type(4))) float f32x4;

// ---- helpers ----
__device__ __forceinline__ unsigned fkey(float f) {
    unsigned b = __float_as_uint(f);
    return (b & 0x80000000u) ? ~b : (b | 0x80000000u);
}
__device__ __forceinline__ float kinv(unsigned k) {
    unsigned b = (k & 0x80000000u) ? (k ^ 0x80000000u) : ~k;
    return __uint_as_float(b);
}
__device__ __forceinline__ unsigned short f2bf(float f) {
    unsigned u = __float_as_uint(f);
    return (unsigned short)((u + 0x7FFFu + ((u >> 16) & 1u)) >> 16);
}
__device__ __forceinline__ float bf2f(unsigned u) {
    return __uint_as_float(u << 16);
}
__device__ __forceinline__ unsigned fkey16(unsigned b) {
    return (b & 0x8000u) ? (~b & 0xFFFFu) : (b | 0x8000u);
}
__device__ __forceinline__ float kval16(unsigned k) {
    unsigned b = (k & 0x8000u) ? (k ^ 0x8000u) : (~k & 0xFFFFu);
    return bf2f(b);
}
__device__ __forceinline__ void gload_lds16(const void* g, void* l) {
    __builtin_amdgcn_global_load_lds(
        (const __attribute__((address_space(1))) void*)g,
        (__attribute__((address_space(3))) void*)l, 16, 0, 0);
}
__device__ __forceinline__ unsigned pack_cand(unsigned bits, int idx) {
    return (fkey16(bits) << 16) | (unsigned)(idx ^ 0x3FFF);
}
__device__ __forceinline__ int   cidx_of(unsigned p) { return (int)((p & 0xFFFFu) ^ 0x3FFFu); }
__device__ __forceinline__ float cval_of(unsigned p) { return kval16(p >> 16); }

// =====================================================================
// init: wsq = 0
// =====================================================================
__global__ void init_wsq(float* wsq) { if (threadIdx.x == 0) wsq[0] = 0.f; }

// =====================================================================
// Fused: W -> bf16 AND sum-of-squares (one read of W)
// =====================================================================
__global__ __launch_bounds__(256)
void cvt_w_sq(const float* __restrict__ W, unsigned short* __restrict__ Wb,
              float* __restrict__ wsq, int n4)
{
    __shared__ float s_[4];
    const int tid = threadIdx.x, lane = tid & 63, wid = tid >> 6;
    float q = 0.f;
    for (int i = blockIdx.x * 256 + tid; i < n4; i += gridDim.x * 256) {
        float4 v = ((const float4*)W)[i];
        ushort4 o;
        o.x = f2bf(v.x); o.y = f2bf(v.y); o.z = f2bf(v.z); o.w = f2bf(v.w);
        ((ushort4*)Wb)[i] = o;
        q = fmaf(v.x, v.x, q); q = fmaf(v.y, v.y, q);
        q = fmaf(v.z, v.z, q); q = fmaf(v.w, v.w, q);
    }
    #pragma unroll
    for (int o = 32; o; o >>= 1) q += __shfl_down(q, o);
    if (lane == 0) s_[wid] = q;
    __syncthreads();
    if (tid == 0) atomicAdd(wsq, s_[0] + s_[1] + s_[2] + s_[3]);
}

// =====================================================================
// x -> bf16 + per-row tau = Z * ||x_row|| * sigma_w ; zero cnt[row]
// =====================================================================
__global__ __launch_bounds__(256)
void cvt_x_tau(const float* __restrict__ x, unsigned short* __restrict__ Xb,
               const float* __restrict__ wsq, float* __restrict__ tau,
               int* __restrict__ cnt, int nw_total)
{
    __shared__ float s_[4];
    const int row = blockIdx.x, tid = threadIdx.x;
    const int lane = tid & 63, wid = tid >> 6;
    float4 v = ((const float4*)x)[row * 256 + tid];
    ushort4 o;
    o.x = f2bf(v.x); o.y = f2bf(v.y); o.z = f2bf(v.z); o.w = f2bf(v.w);
    ((ushort4*)Xb)[row * 256 + tid] = o;
    float q = fmaf(v.x, v.x, fmaf(v.y, v.y, fmaf(v.z, v.z, v.w * v.w)));
    #pragma unroll
    for (int of = 32; of; of >>= 1) q += __shfl_down(q, of);
    if (lane == 0) s_[wid] = q;
    __syncthreads();
    if (tid == 0) {
        float sx = s_[0] + s_[1] + s_[2] + s_[3];
        tau[row] = ZTAU * sqrtf(sx * (wsq[0] / (float)nw_total));
        cnt[row] = 0;
    }
}

// =====================================================================
// Kernel 1: bf16 MFMA encode GEMM.
//  - T2 XOR-swizzled LDS (pre-swizzled GLOBAL source + swizzled ds_read;
//    LDS dest stays linear as global_load_lds requires) -> 16-way bank
//    conflict on fragment reads becomes 2-way (free).
//  - nontemporal zero-write of sparse region at entry (overlaps k-loop)
//  - 2D supertile XCD mapping (r14): FETCH ~111 MB
//  - epilogue: candidate appends only.
// =====================================================================
__global__ __launch_bounds__(256)
void encode_fused(const unsigned short* __restrict__ Xb,
                  const unsigned short* __restrict__ Wb,
                  const float* __restrict__ be,
                  const float* __restrict__ taug,
                  float* __restrict__ out,
                  int* __restrict__ cnt, unsigned* __restrict__ cand)
{
    __shared__ unsigned short Al[BM * BK];
    __shared__ unsigned short Bl[BN * BK];

    // ---- supertile mapping: 4096 blocks, 8 XCDs x 512, supertile 8bm x 4bn
    const int xcd = blockIdx.x & 7;
    const int c   = blockIdx.x >> 3;
    const int stm = c >> 7;
    const int r_  = c & 127;
    const int stn = r_ >> 5;
    const int w_  = r_ & 31;
    const int bm  = stm * 8 + (w_ & 7);
    const int bn  = xcd * 16 + stn * 4 + (w_ >> 3);

    const int tid  = threadIdx.x;
    const int wid  = tid >> 6;
    const int lane = tid & 63;
    const int wr   = wid >> 1, wc = wid & 1;

    // ---- nontemporal zero-write of this block's 128x128 sparse region
    {
        float* sp = out + (size_t)N_TOK * D_MODEL;
        const f32x4 z = (f32x4){0.f, 0.f, 0.f, 0.f};
        #pragma unroll
        for (int it = 0; it < 16; ++it) {
            int e = it * 256 + tid;
            int rr = e >> 5;
            int cB = e & 31;
            __builtin_nontemporal_store(
                z, (f32x4*)&sp[(size_t)(bm * BM + rr) * N_FEAT + bn * BN] + cB);
        }
    }

    const size_t Abase = (size_t)(bm * BM) * D_MODEL;
    const size_t Bbase = (size_t)(bn * BN) * D_MODEL;

    f32x4 acc[4][4];
    #pragma unroll
    for (int m = 0; m < 4; ++m)
        #pragma unroll
        for (int n = 0; n < 4; ++n)
            acc[m][n] = (f32x4){0.f, 0.f, 0.f, 0.f};

    // staging: lane -> row (c*8 + lane>>3); global 16B-slot PRE-SWIZZLED
    // by the row parity so the (linear) LDS ends up XOR-swizzled.
    const int srow = (lane >> 3);                         // row within 8-chunk
    const int scol = ((lane & 7) ^ srow) * 8;             // swizzled 8-elem slot
    const int g16  = lane >> 4;                           // 0..3
    const int x7   = lane & 7;                            // == row&7 of frag rows

    for (int k0 = 0; k0 < D_MODEL; k0 += BK) {
        #pragma unroll
        for (int c4 = 0; c4 < 4; ++c4) {
            const int cc  = wid * 4 + c4;
            const int row = cc * 8 + srow;
            gload_lds16(Xb + Abase + (size_t)row * D_MODEL + k0 + scol, &Al[cc * 512]);
            gload_lds16(Wb + Bbase + (size_t)row * D_MODEL + k0 + scol, &Bl[cc * 512]);
        }
        __syncthreads();

        // fragment reads with the matching XOR: slot = (ks*4+g16) ^ (row&7)
        bf16x8 af[2][4], bf[2][4];
        #pragma unroll
        for (int ks = 0; ks < 2; ++ks) {
            #pragma unroll
            for (int m = 0; m < 4; ++m) {
                const int rowA = wr * 64 + m * 16 + (lane & 15);
                const int slot = (ks * 4 + g16) ^ x7;
                af[ks][m] = *(const bf16x8*)((const char*)Al + rowA * 128 + slot * 16);
            }
            #pragma unroll
            for (int n = 0; n < 4; ++n) {
                const int rowB = wc * 64 + n * 16 + (lane & 15);
                const int slot = (ks * 4 + g16) ^ x7;
                bf[ks][n] = *(const bf16x8*)((const char*)Bl + rowB * 128 + slot * 16);
            }
        }
        #pragma unroll
        for (int ks = 0; ks < 2; ++ks)
            #pragma unroll
            for (int m = 0; m < 4; ++m)
                #pragma unroll
                for (int n = 0; n < 4; ++n)
                    acc[m][n] = __builtin_amdgcn_mfma_f32_16x16x32_bf16(af[ks][m], bf[ks][n], acc[m][n], 0, 0, 0);
        __syncthreads();
    }

    // ---- epilogue: candidate appends only
    const int c0 = bn * BN + wc * 64 + (lane & 15);
    #pragma unroll
    for (int m = 0; m < 4; ++m) {
        const int r0 = bm * BM + wr * 64 + m * 16 + (lane >> 4) * 4;
        #pragma unroll
        for (int r = 0; r < 4; ++r) {
            const int row = r0 + r;
            const float tau = taug[row];
            #pragma unroll
            for (int n = 0; n < 4; ++n) {
                const int col = c0 + n * 16;
                const unsigned bits = (unsigned)f2bf(acc[m][n][r] + be[col]);
                if (bf2f(bits) >= tau) {
                    int p = atomicAdd(&cnt[row], 1);
                    if (p < CAP)
                        cand[(size_t)row * CAP + p] = pack_cand(bits, col);
                }
            }
        }
    }
}

// =====================================================================
// Select+decode: exact top-64 from the candidate list. Fallback rescans
// RECOMPUTE the row (bf16 inputs, f32 accum) -- statistically never.
// f64 band refinement, deterministic slots, scatter, decode.
// =====================================================================
__global__ __launch_bounds__(256)
void select_decode(const float* __restrict__ x, const float* __restrict__ W,
                   const unsigned short* __restrict__ Wb,
                   const float* __restrict__ be, const float* __restrict__ bd,
                   const float* __restrict__ taug, const int* __restrict__ cntg,
                   const unsigned* __restrict__ candg, float* __restrict__ out)
{
    const int row = blockIdx.x, tid = threadIdx.x;
    const int lane = tid & 63, wid = tid >> 6;
    float* recon = out + (size_t)row * D_MODEL;
    float* srow  = out + (size_t)N_TOK * D_MODEL + (size_t)row * N_FEAT;

    __shared__ float    xs[D_MODEL];
    __shared__ unsigned cd[CAP];
    __shared__ double   v64[CAP];
    __shared__ int      tk_idx[K_TOP];
    __shared__ float    tk_val[K_TOP];
    __shared__ unsigned shT;
    __shared__ int      nc_sh, ns_sh;

    *(float4*)&xs[tid * 4] = *(const float4*)&x[(size_t)row * D_MODEL + tid * 4];
    if (tid < K_TOP) { tk_idx[tid] = -1; tk_val[tid] = 0.f; }

    int ncTrue = cntg[row];
    int nc = min(ncTrue, CAP);
    float thr = taug[row];
    if (tid < nc) cd[tid] = candg[(size_t)row * CAP + tid];
    __syncthreads();

    // ---- rare: adjust thr until 64 <= ncTrue <= CAP (recompute row)
    for (int t = 0; t < 10 && (ncTrue < K_TOP || ncTrue > CAP); ++t) {
        thr += (ncTrue > CAP) ? 0.08f : -0.08f;
        if (tid == 0) nc_sh = 0;
        __syncthreads();
        for (int f = tid; f < N_FEAT; f += 256) {
            const u16x8* wr8 = (const u16x8*)&Wb[(size_t)f * D_MODEL];
            float s = 0.f;
            for (int d8 = 0; d8 < D_MODEL / 8; ++d8) {
                u16x8 w8 = wr8[d8];
                #pragma unroll
                for (int k = 0; k < 8; ++k)
                    s = fmaf(bf2f((unsigned)(unsigned short)w8[k]),
                             bf2f((unsigned)f2bf(xs[d8 * 8 + k])), s);
            }
            unsigned bits = (unsigned)f2bf(s + be[f]);
            if (bf2f(bits) >= thr) {
                int p = atomicAdd(&nc_sh, 1);
                if (p < CAP) cd[p] = pack_cand(bits, f);
            }
        }
        __syncthreads();
        ncTrue = nc_sh; nc = min(ncTrue, CAP);
        __syncthreads();
    }

    // ---- T' = exact 64th largest (packed: value desc, idx asc)
    if (tid < nc) {
        unsigned me = cd[tid];
        int r = 0;
        for (int j = 0; j < nc; ++j) r += (cd[j] > me);
        if (r == K_TOP - 1) shT = me;
    }
    __syncthreads();
    const float Tval = cval_of(shT);

    // ---- rare: thr too high to cover the band -> one full recompute
    if (thr > Tval - DELTA) {
        const float thr2 = Tval - DELTA;
        if (tid == 0) nc_sh = 0;
        __syncthreads();
        for (int f = tid; f < N_FEAT; f += 256) {
            const u16x8* wr8 = (const u16x8*)&Wb[(size_t)f * D_MODEL];
            float s = 0.f;
            for (int d8 = 0; d8 < D_MODEL / 8; ++d8) {
                u16x8 w8 = wr8[d8];
                #pragma unroll
                for (int k = 0; k < 8; ++k)
                    s = fmaf(bf2f((unsigned)(unsigned short)w8[k]),
                             bf2f((unsigned)f2bf(xs[d8 * 8 + k])), s);
            }
            unsigned bits = (unsigned)f2bf(s + be[f]);
            if (bf2f(bits) >= thr2) {
                int p = atomicAdd(&nc_sh, 1);
                if (p < CAP) cd[p] = pack_cand(bits, f);
            }
        }
        __syncthreads();
        nc = min(nc_sh, CAP);
        __syncthreads();
    }

    // ---- classify
    if (tid == 0) ns_sh = 0;
    __syncthreads();
    const float sureT = Tval + DELTA, loT = Tval - DELTA;
    if (tid < nc && cval_of(cd[tid]) > sureT) atomicAdd(&ns_sh, 1);

    // ---- f64 refinement of the band (exact f32 inputs)
    for (int c = wid; c < nc; c += 4) {
        float cv = cval_of(cd[c]);
        if (cv > sureT || cv < loT) continue;
        int fi = cidx_of(cd[c]);
        const float* wr = &W[(size_t)fi * D_MODEL];
        double s = 0.0;
        #pragma unroll
        for (int e = 0; e < 16; ++e) {
            int d = lane + e * 64;
            s += (double)xs[d] * (double)wr[d];
        }
        #pragma unroll
        for (int o = 32; o; o >>= 1) s += __shfl_down(s, o);
        if (lane == 0) v64[c] = s + (double)be[fi];
    }
    __syncthreads();
    const int n_sure = ns_sh;

    // ---- deterministic slot assignment
    if (tid < nc) {
        const unsigned me = cd[tid];
        const float v = cval_of(me);
        const int fi = cidx_of(me);
        if (v > sureT) {
            int r = 0;
            for (int j = 0; j < nc; ++j) {
                unsigned cj = cd[j];
                r += (cval_of(cj) > sureT) && (cidx_of(cj) < fi);
            }
            tk_idx[r] = fi;
            tk_val[r] = fmaxf(v, 0.f);
        } else if (v >= loT) {
            const double mv = v64[tid];
            int r = 0;
            for (int j = 0; j < nc; ++j) {
                unsigned cj = cd[j];
                float vj = cval_of(cj);
                if (vj > sureT || vj < loT) continue;
                double xv = v64[j];
                r += (xv > mv) || (xv == mv && cidx_of(cj) < fi);
            }
            if (r < K_TOP - n_sure) {
                tk_idx[n_sure + r] = fi;
                tk_val[n_sure + r] = fmaxf((float)mv, 0.f);
            }
        }
    }
    __syncthreads();

    // ---- scatter the 64 sparse values (zeros already written by encode)
    if (tid < K_TOP && tk_idx[tid] >= 0)
        srow[tk_idx[tid]] = tk_val[tid];

    // ---- decode: recon[d] = bd[d] + sum_j tk_val[j] * Wb[tk_idx[j]][d]
    const int d4 = tid * 4;
    float4 a = *(const float4*)&bd[d4];
    #pragma unroll 8
    for (int j = 0; j < K_TOP; ++j) {
        const float v = tk_val[j];
        const int ix = tk_idx[j] < 0 ? 0 : tk_idx[j];
        ushort4 w4 = *(const ushort4*)&Wb[(size_t)ix * D_MODEL + d4];
        a.x = fmaf(v, bf2f((unsigned)w4.x), a.x);
        a.y = fmaf(v, bf2f((unsigned)w4.y), a.y);
        a.z = fmaf(v, bf2f((unsigned)w4.z), a.z);
        a.w = fmaf(v, bf2f((unsigned)w4.w), a.w);
    }
    *(float4*)&recon[d4] = a;
}

// =====================================================================
// Tier C fallbacks (no workspace): f32 GEMM + f32 radix topk
// =====================================================================
__global__ __launch_bounds__(256)
void encode_gemm(const float* __restrict__ x, const float* __restrict__ W,
                 const float* __restrict__ be, float* __restrict__ h)
{
    __shared__ float As[32][68];
    __shared__ float Bs[32][68];

    const int bm = blockIdx.x % (N_TOK / 64);
    const int bn = blockIdx.x / (N_TOK / 64);
    const int tid = threadIdx.x;
    const int tx = tid & 15, ty = tid >> 4;

    const float* Ab = x + (size_t)(bm * 64) * D_MODEL;
    const float* Bb = W + (size_t)(bn * 64) * D_MODEL;

    float acc[4][4] = {};

    for (int k0 = 0; k0 < D_MODEL; k0 += 32) {
        #pragma unroll
        for (int i = 0; i < 8; ++i) {
            int e = tid + i * 256;
            int kk = e & 31, m = e >> 5;
            As[kk][m] = Ab[(size_t)m * D_MODEL + k0 + kk];
            Bs[kk][m] = Bb[(size_t)m * D_MODEL + k0 + kk];
        }
        __syncthreads();
        #pragma unroll
        for (int kk = 0; kk < 32; ++kk) {
            float4 a4 = *(const float4*)&As[kk][ty * 4];
            float4 b4 = *(const float4*)&Bs[kk][tx * 4];
            float a[4] = {a4.x, a4.y, a4.z, a4.w};
            float b[4] = {b4.x, b4.y, b4.z, b4.w};
            #pragma unroll
            for (int i = 0; i < 4; ++i)
                #pragma unroll
                for (int j = 0; j < 4; ++j)
                    acc[i][j] = fmaf(a[i], b[j], acc[i][j]);
        }
        __syncthreads();
    }

    const int rowb = bm * 64 + ty * 4;
    const int colb = bn * 64 + tx * 4;
    float4 bev = *(const float4*)&be[colb];
    float bb[4] = {bev.x, bev.y, bev.z, bev.w};
    #pragma unroll
    for (int i = 0; i < 4; ++i) {
        float4 o;
        o.x = acc[i][0] + bb[0];
        o.y = acc[i][1] + bb[1];
        o.z = acc[i][2] + bb[2];
        o.w = acc[i][3] + bb[3];
        *(float4*)&h[(size_t)(rowb + i) * N_FEAT + colb] = o;
    }
}

__global__ __launch_bounds__(256)
void topk_decode(const float* __restrict__ hsrc,
                 const float* __restrict__ x, const float* __restrict__ W,
                 const float* __restrict__ be, const float* __restrict__ bd,
                 float* __restrict__ out)
{
    const int row = blockIdx.x;
    const int tid = threadIdx.x;
    float* recon = out + (size_t)row * D_MODEL;
    float* srow  = out + (size_t)N_TOK * D_MODEL + (size_t)row * N_FEAT;
    const float* hr = hsrc + (size_t)row * N_FEAT;

    unsigned key[16][4];
    #pragma unroll
    for (int i = 0; i < 16; ++i) {
        float4 v = ((const float4*)hr)[tid + i * 256];
        key[i][0] = fkey(v.x); key[i][1] = fkey(v.y);
        key[i][2] = fkey(v.z); key[i][3] = fkey(v.w);
    }

    __shared__ unsigned hist[256];
    __shared__ unsigned sh_prefix;
    __shared__ int sh_need;
    __shared__ float xs[D_MODEL];
    __shared__ int      cand_idx[CAND_MAX];
    __shared__ unsigned cand_key[CAND_MAX];
    __shared__ double   cand_val[CAND_MAX];
    __shared__ int nc_sh, nsure_sh;
    __shared__ int   tk_idx[K_TOP];
    __shared__ float tk_val[K_TOP];

    *(float4*)&xs[tid * 4] = *(const float4*)&x[(size_t)row * D_MODEL + tid * 4];
    if (tid == 0) { nc_sh = 0; nsure_sh = 0; }
    if (tid < K_TOP) { tk_val[tid] = 0.0f; tk_idx[tid] = -1; }

    unsigned prefix = 0, maskv = 0;
    int need = K_TOP;
    for (int pass = 0; pass < 4; ++pass) {
        const int shift = 24 - 8 * pass;
        hist[tid] = 0;
        __syncthreads();
        #pragma unroll
        for (int i = 0; i < 16; ++i)
            #pragma unroll
            for (int j = 0; j < 4; ++j) {
                unsigned k = key[i][j];
                if ((k & maskv) == prefix)
                    atomicAdd(&hist[(k >> shift) & 255u], 1u);
            }
        __syncthreads();
        if (tid == 0) {
            unsigned cum = 0;
            int d = 255;
            for (; d >= 0; --d) {
                unsigned c = hist[d];
                if (cum + c >= (unsigned)need) break;
                cum += c;
            }
            if (d < 0) d = 0;
            sh_need = need - (int)cum;
            sh_prefix = prefix | ((unsigned)d << shift);
        }
        __syncthreads();
        prefix = sh_prefix;
        need = sh_need;
        maskv |= (0xFFu << shift);
    }
    const unsigned T  = prefix;
    const unsigned Tl = fkey(kinv(T) - DELTA);
    const unsigned Th = fkey(kinv(T) + DELTA);

    #pragma unroll
    for (int i = 0; i < 16; ++i)
        #pragma unroll
        for (int j = 0; j < 4; ++j)
            if (key[i][j] >= Tl) {
                int p = atomicAdd(&nc_sh, 1);
                if (p < CAND_MAX) {
                    cand_idx[p] = (tid + i * 256) * 4 + j;
                    cand_key[p] = key[i][j];
                }
            }
    __syncthreads();
    int nc = nc_sh; if (nc > CAND_MAX) nc = CAND_MAX;

    if (tid < nc && cand_key[tid] > Th) atomicAdd(&nsure_sh, 1);
    __syncthreads();
    const int n_sure = nsure_sh;

    {
        const int lane = tid & 63, wave = tid >> 6;
        for (int c = wave; c < nc; c += 4) {
            if (cand_key[c] > Th) continue;
            const float* wr = &W[(size_t)cand_idx[c] * D_MODEL];
            double s = 0.0;
            #pragma unroll
            for (int e = 0; e < 16; ++e) {
                int d = lane + e * 64;
                s += (double)xs[d] * (double)wr[d];
            }
            #pragma unroll
            for (int o = 32; o; o >>= 1) s += __shfl_down(s, o);
            if (lane == 0) cand_val[c] = s + (double)be[cand_idx[c]];
        }
    }
    __syncthreads();

    if (tid < nc) {
        const unsigned ki = cand_key[tid];
        const int fi = cand_idx[tid];
        if (ki > Th) {
            int r = 0;
            for (int j = 0; j < nc; ++j)
                r += (cand_key[j] > Th) && (cand_idx[j] < fi);
            tk_idx[r] = fi;
            tk_val[r] = fmaxf(kinv(ki), 0.0f);
        } else {
            const double v = cand_val[tid];
            int r = 0;
            for (int j = 0; j < nc; ++j) {
                if (cand_key[j] > Th) continue;
                double vj = cand_val[j];
                r += (vj > v) || (vj == v && cand_idx[j] < fi);
            }
            if (r < K_TOP - n_sure) {
                tk_idx[n_sure + r] = fi;
                tk_val[n_sure + r] = fmaxf((float)v, 0.0f);
            }
        }
    }
    __syncthreads();

    #pragma unroll
    for (int i = 0; i < 16; ++i) {
        float ov[4];
        #pragma unroll
        for (int j = 0; j < 4; ++j) {
            unsigned k = key[i][j];
            int f = (tid + i * 256) * 4 + j;
            float val = 0.0f;
            if (k >= Tl) {
                for (int q = 0; q < K_TOP; ++q)
                    if (tk_idx[q] == f) { val = tk_val[q]; break; }
            }
            ov[j] = val;
        }
        float4 o; o.x = ov[0]; o.y = ov[1]; o.z = ov[2]; o.w = ov[3];
        ((float4*)srow)[tid + i * 256] = o;
    }
    __syncthreads();

    const int d4 = tid * 4;
    float4 a = *(const float4*)&bd[d4];
    #pragma unroll 8
    for (int j = 0; j < K_TOP; ++j) {
        float v = tk_val[j];
        int ix = tk_idx[j] < 0 ? 0 : tk_idx[j];
        const float4 w = *(const float4*)&W[(size_t)ix * D_MODEL + d4];
        a.x = fmaf(v, w.x, a.x);
        a.y = fmaf(v, w.y, a.y);
        a.z = fmaf(v, w.z, a.z);
        a.w = fmaf(v, w.w, a.w);
    }
    *(float4*)&recon[d4] = a;
}

extern "C" void kernel_launch(void* const* d_in, const int* in_sizes, int n_in,
                              void* d_out, int out_size, void* d_ws, size_t ws_size,
                              hipStream_t stream) {
    const float* x     = (const float*)d_in[0];
    const float* W_enc = (const float*)d_in[1];
    const float* b_enc = (const float*)d_in[2];
    const float* b_dec = (const float*)d_in[4];
    float* out = (float*)d_out;

    float* h_out_region = out + (size_t)N_TOK * D_MODEL;

    const size_t nx = (size_t)N_TOK * D_MODEL;          // 4.19M
    const size_t nw = (size_t)N_FEAT * D_MODEL;         // 16.8M
    const size_t bf_bytes   = (nx + nw) * sizeof(unsigned short);     // 40 MB
    const size_t cand_bytes = (size_t)N_TOK * CAP * sizeof(unsigned); // 4 MB
    const size_t misc_bytes = (size_t)N_TOK * (sizeof(float) + sizeof(int)) + 64;
    const size_t needA = bf_bytes + cand_bytes + misc_bytes;          // ~44 MB

    if (ws_size >= needA) {
        // ---- tier A: no-h pipeline, zeros fused into encode (nt stores)
        unsigned short* Xb  = (unsigned short*)d_ws;
        unsigned short* Wb  = Xb + nx;
        unsigned* cand = (unsigned*)((char*)d_ws + bf_bytes);
        float*    tau  = (float*)((char*)cand + cand_bytes);
        int*      cnt  = (int*)(tau + N_TOK);
        float*    wsq  = (float*)(cnt + N_TOK);

        init_wsq<<<1, 64, 0, stream>>>(wsq);
        cvt_w_sq<<<512, 256, 0, stream>>>(W_enc, Wb, wsq, (int)(nw / 4));
        cvt_x_tau<<<N_TOK, 256, 0, stream>>>(x, Xb, wsq, tau, cnt, (int)nw);
        encode_fused<<<(N_TOK / BM) * (N_FEAT / BN), 256, 0, stream>>>(
            Xb, Wb, b_enc, tau, out, cnt, cand);
        select_decode<<<N_TOK, 256, 0, stream>>>(x, W_enc, Wb, b_enc, b_dec,
                                                 tau, cnt, cand, out);
    } else {
        // ---- tier C: pure f32
        encode_gemm<<<(N_TOK / 64) * (N_FEAT / 64), 256, 0, stream>>>(x, W_enc, b_enc, h_out_region);
        topk_decode<<<N_TOK, 256, 0, stream>>>(h_out_region, x, W_enc, b_enc, b_dec, out);
    }
}